// Round 1
// baseline (123.477 us; speedup 1.0000x reference)
//
#include <hip/hip_runtime.h>

// CompositeLoss: boundary-weighted BCE + Dice over (32,1,512,512)
// pred: float32 uniform [0,1), target: int32 binary {0,1}
// out: [total, bce, dice] float32

#define BB 32
#define HH 512
#define WW 512
#define N_TOTAL (BB * HH * WW)
#define SEG 8
#define W8 (WW / SEG)
#define NSEG (BB * HH * W8)

__global__ void zero_acc_kernel(double* acc) {
    if (threadIdx.x < 4) acc[threadIdx.x] = 0.0;
}

__global__ __launch_bounds__(256) void loss_main_kernel(
        const float* __restrict__ pred,
        const int* __restrict__ target,
        double* __restrict__ acc) {
    float wbce = 0.f, inter = 0.f, sp = 0.f;
    int st_i = 0;

    for (int seg = blockIdx.x * blockDim.x + threadIdx.x; seg < NSEG;
         seg += gridDim.x * blockDim.x) {
        int w8  = seg % W8;
        int tmp = seg / W8;
        int h   = tmp % HH;
        int b   = tmp / HH;
        int w0  = w8 * SEG;

        const size_t imgbase = (size_t)b * HH;
        const size_t base = (imgbase + h) * WW + w0;

        // pred: 8 contiguous floats
        float4 p0 = *(const float4*)(pred + base);
        float4 p1 = *(const float4*)(pred + base + 4);
        float pv[8] = {p0.x, p0.y, p0.z, p0.w, p1.x, p1.y, p1.z, p1.w};

        // target rows h-1, h, h+1 (clamped; duplicate rows don't change OR/AND)
        int hm = (h > 0) ? h - 1 : 0;
        int hp = (h < HH - 1) ? h + 1 : HH - 1;
        const int* row0 = target + (imgbase + hm) * WW;
        const int* row1 = target + (imgbase + h)  * WW;
        const int* row2 = target + (imgbase + hp) * WW;
        const int* rows[3] = {row0, row1, row2};

        int v[3][10];  // columns w0-1 .. w0+8 (clamped)
        #pragma unroll
        for (int r = 0; r < 3; ++r) {
            const int* row = rows[r];
            int4 a = *(const int4*)(row + w0);
            int4 c = *(const int4*)(row + w0 + 4);
            v[r][1] = a.x; v[r][2] = a.y; v[r][3] = a.z; v[r][4] = a.w;
            v[r][5] = c.x; v[r][6] = c.y; v[r][7] = c.z; v[r][8] = c.w;
            v[r][0] = (w0 > 0) ? row[w0 - 1] : a.x;                // clamp left
            v[r][9] = (w0 + SEG < WW) ? row[w0 + SEG] : c.w;       // clamp right
        }

        // vertical OR/AND (separable morphology)
        int cor[10], cand[10];
        #pragma unroll
        for (int i = 0; i < 10; ++i) {
            cor[i]  = v[0][i] | v[1][i] | v[2][i];
            cand[i] = v[0][i] & v[1][i] & v[2][i];
        }

        #pragma unroll
        for (int i = 0; i < 8; ++i) {
            int o = cor[i]  | cor[i + 1]  | cor[i + 2];
            int a = cand[i] & cand[i + 1] & cand[i + 2];
            float wgt = (o != a) ? 3.0f : 1.0f;   // boundary weight
            int t = v[1][i + 1];
            float p = pv[i];
            float pc = fminf(fmaxf(p, 1e-7f), 1.0f - 1e-7f);
            float x = t ? pc : (1.0f - pc);
            wbce += wgt * (-__logf(x));
            if (t) inter += p;
            sp += p;
            st_i += t;
        }
    }

    // wave (64-lane) shuffle reduction
    float st = (float)st_i;
    #pragma unroll
    for (int off = 32; off > 0; off >>= 1) {
        wbce  += __shfl_down(wbce,  off);
        inter += __shfl_down(inter, off);
        sp    += __shfl_down(sp,    off);
        st    += __shfl_down(st,    off);
    }

    __shared__ float smem[4][4];  // 4 waves per 256-thread block
    int wave = threadIdx.x >> 6;
    int lane = threadIdx.x & 63;
    if (lane == 0) {
        smem[wave][0] = wbce; smem[wave][1] = inter;
        smem[wave][2] = sp;   smem[wave][3] = st;
    }
    __syncthreads();
    if (threadIdx.x == 0) {
        float a0 = 0, a1 = 0, a2 = 0, a3 = 0;
        #pragma unroll
        for (int wv = 0; wv < 4; ++wv) {
            a0 += smem[wv][0]; a1 += smem[wv][1];
            a2 += smem[wv][2]; a3 += smem[wv][3];
        }
        atomicAdd(&acc[0], (double)a0);
        atomicAdd(&acc[1], (double)a1);
        atomicAdd(&acc[2], (double)a2);
        atomicAdd(&acc[3], (double)a3);
    }
}

__global__ void finalize_kernel(const double* __restrict__ acc,
                                float* __restrict__ out) {
    if (threadIdx.x == 0) {
        double bce = acc[0] / (double)N_TOTAL;
        double dice_coef = (2.0 * acc[1] + 1e-6) / (acc[2] + acc[3] + 1e-6);
        double dice = 1.0 - dice_coef;
        double total = 0.5 * bce + 0.5 * dice;
        out[0] = (float)total;
        out[1] = (float)bce;
        out[2] = (float)dice;
    }
}

extern "C" void kernel_launch(void* const* d_in, const int* in_sizes, int n_in,
                              void* d_out, int out_size, void* d_ws, size_t ws_size,
                              hipStream_t stream) {
    const float* pred  = (const float*)d_in[0];
    const int*  target = (const int*)d_in[1];
    float* out = (float*)d_out;
    double* acc = (double*)d_ws;

    zero_acc_kernel<<<1, 64, 0, stream>>>(acc);
    loss_main_kernel<<<2048, 256, 0, stream>>>(pred, target, acc);
    finalize_kernel<<<1, 64, 0, stream>>>(acc, out);
}

// Round 2
// 27.294 us; speedup vs baseline: 4.5239x; 4.5239x over previous
//
#include <hip/hip_runtime.h>

// CompositeLoss: boundary-weighted BCE + Dice over (32,1,512,512)
// pred: float32 uniform [0,1), target: int32 binary {0,1}
// out: [total, bce, dice] float32
//
// R1 design: all named registers (no local arrays -> no scratch),
// per-block partials in d_ws (no global atomics), 2-kernel reduce.

#define BB 32
#define HH 512
#define WW 512
#define N_TOTAL (BB * HH * WW)
#define SEG 8
#define W8 (WW / SEG)            // 64 segments per row
#define NSEG (BB * HH * W8)      // 1,048,576
#define NBLK 2048

__global__ __launch_bounds__(256) void loss_main_kernel(
        const float* __restrict__ pred,
        const int* __restrict__ target,
        double* __restrict__ partials) {
    float wbce = 0.f, inter = 0.f, sp = 0.f;
    int st_i = 0;

    const int stride = gridDim.x * blockDim.x;   // 524288 -> exactly 2 iters
    for (int seg = blockIdx.x * blockDim.x + threadIdx.x; seg < NSEG;
         seg += stride) {
        const int w0 = (seg & (W8 - 1)) << 3;    // 0..504
        const int h  = (seg >> 6) & (HH - 1);
        const int b  = seg >> 15;

        const size_t rowbase = ((size_t)(b * HH + h)) * WW;

        const float4 p0 = *(const float4*)(pred + rowbase + w0);
        const float4 p1 = *(const float4*)(pred + rowbase + w0 + 4);

        const int* rowC = target + rowbase;                       // row h
        const int* rowU = (h > 0)      ? rowC - WW : rowC;        // row h-1 (clamped)
        const int* rowD = (h < HH - 1) ? rowC + WW : rowC;        // row h+1 (clamped)

        const int4 uA = *(const int4*)(rowU + w0);
        const int4 uB = *(const int4*)(rowU + w0 + 4);
        const int4 cA = *(const int4*)(rowC + w0);
        const int4 cB = *(const int4*)(rowC + w0 + 4);
        const int4 dA = *(const int4*)(rowD + w0);
        const int4 dB = *(const int4*)(rowD + w0 + 4);

        // halo columns w0-1 and w0+8 (clamped at image edges)
        int lU, lC, lD, rU, rC, rD;
        if (w0 > 0) { lU = rowU[w0 - 1]; lC = rowC[w0 - 1]; lD = rowD[w0 - 1]; }
        else        { lU = uA.x;         lC = cA.x;         lD = dA.x; }
        if (w0 + SEG < WW) { rU = rowU[w0 + SEG]; rC = rowC[w0 + SEG]; rD = rowD[w0 + SEG]; }
        else               { rU = uB.w;           rC = cB.w;           rD = dB.w; }

        // vertical OR / AND (separable 3x3 morphology), all named
        const int o0 = uA.x | cA.x | dA.x,  n0 = uA.x & cA.x & dA.x;
        const int o1 = uA.y | cA.y | dA.y,  n1 = uA.y & cA.y & dA.y;
        const int o2 = uA.z | cA.z | dA.z,  n2 = uA.z & cA.z & dA.z;
        const int o3 = uA.w | cA.w | dA.w,  n3 = uA.w & cA.w & dA.w;
        const int o4 = uB.x | cB.x | dB.x,  n4 = uB.x & cB.x & dB.x;
        const int o5 = uB.y | cB.y | dB.y,  n5 = uB.y & cB.y & dB.y;
        const int o6 = uB.z | cB.z | dB.z,  n6 = uB.z & cB.z & dB.z;
        const int o7 = uB.w | cB.w | dB.w,  n7 = uB.w & cB.w & dB.w;
        const int oL = lU | lC | lD,        nL = lU & lC & lD;
        const int oR = rU | rC | rD,        nR = rU & rC & rD;

        // horizontal window -> boundary flag per pixel
        const int e0 = (oL | o0 | o1) != (nL & n0 & n1);
        const int e1 = (o0 | o1 | o2) != (n0 & n1 & n2);
        const int e2 = (o1 | o2 | o3) != (n1 & n2 & n3);
        const int e3 = (o2 | o3 | o4) != (n2 & n3 & n4);
        const int e4 = (o3 | o4 | o5) != (n3 & n4 & n5);
        const int e5 = (o4 | o5 | o6) != (n4 & n5 & n6);
        const int e6 = (o5 | o6 | o7) != (n5 & n6 & n7);
        const int e7 = (o6 | o7 | oR) != (n6 & n7 & nR);

#define ACC(T, P, E)                                                   \
        {                                                              \
            const float pc = fminf(fmaxf((P), 1e-7f), 1.0f - 1e-7f);   \
            const float x  = (T) ? pc : (1.0f - pc);                   \
            wbce += ((E) ? 3.0f : 1.0f) * (-__logf(x));                \
            sp += (P);                                                 \
            if (T) inter += (P);                                       \
            st_i += (T);                                               \
        }

        ACC(cA.x, p0.x, e0); ACC(cA.y, p0.y, e1);
        ACC(cA.z, p0.z, e2); ACC(cA.w, p0.w, e3);
        ACC(cB.x, p1.x, e4); ACC(cB.y, p1.y, e5);
        ACC(cB.z, p1.z, e6); ACC(cB.w, p1.w, e7);
#undef ACC
    }

    // wave (64-lane) shuffle reduction
    float st = (float)st_i;
    #pragma unroll
    for (int off = 32; off > 0; off >>= 1) {
        wbce  += __shfl_down(wbce,  off);
        inter += __shfl_down(inter, off);
        sp    += __shfl_down(sp,    off);
        st    += __shfl_down(st,    off);
    }

    __shared__ float smem[4][4];
    const int wave = threadIdx.x >> 6;
    const int lane = threadIdx.x & 63;
    if (lane == 0) {
        smem[wave][0] = wbce; smem[wave][1] = inter;
        smem[wave][2] = sp;   smem[wave][3] = st;
    }
    __syncthreads();
    if (threadIdx.x == 0) {
        float a0 = 0, a1 = 0, a2 = 0, a3 = 0;
        #pragma unroll
        for (int wv = 0; wv < 4; ++wv) {
            a0 += smem[wv][0]; a1 += smem[wv][1];
            a2 += smem[wv][2]; a3 += smem[wv][3];
        }
        double* dst = partials + (size_t)blockIdx.x * 4;
        dst[0] = (double)a0; dst[1] = (double)a1;
        dst[2] = (double)a2; dst[3] = (double)a3;
    }
}

__global__ __launch_bounds__(256) void finalize_kernel(
        const double* __restrict__ partials, float* __restrict__ out) {
    double a0 = 0, a1 = 0, a2 = 0, a3 = 0;
    for (int i = threadIdx.x; i < NBLK; i += 256) {
        const double* src = partials + (size_t)i * 4;
        a0 += src[0]; a1 += src[1]; a2 += src[2]; a3 += src[3];
    }
    #pragma unroll
    for (int off = 32; off > 0; off >>= 1) {
        a0 += __shfl_down(a0, off);
        a1 += __shfl_down(a1, off);
        a2 += __shfl_down(a2, off);
        a3 += __shfl_down(a3, off);
    }
    __shared__ double smem[4][4];
    const int wave = threadIdx.x >> 6;
    const int lane = threadIdx.x & 63;
    if (lane == 0) {
        smem[wave][0] = a0; smem[wave][1] = a1;
        smem[wave][2] = a2; smem[wave][3] = a3;
    }
    __syncthreads();
    if (threadIdx.x == 0) {
        double s0 = 0, s1 = 0, s2 = 0, s3 = 0;
        #pragma unroll
        for (int wv = 0; wv < 4; ++wv) {
            s0 += smem[wv][0]; s1 += smem[wv][1];
            s2 += smem[wv][2]; s3 += smem[wv][3];
        }
        const double bce = s0 / (double)N_TOTAL;
        const double dice_coef = (2.0 * s1 + 1e-6) / (s2 + s3 + 1e-6);
        const double dice = 1.0 - dice_coef;
        const double total = 0.5 * bce + 0.5 * dice;
        out[0] = (float)total;
        out[1] = (float)bce;
        out[2] = (float)dice;
    }
}

extern "C" void kernel_launch(void* const* d_in, const int* in_sizes, int n_in,
                              void* d_out, int out_size, void* d_ws, size_t ws_size,
                              hipStream_t stream) {
    const float* pred  = (const float*)d_in[0];
    const int* target  = (const int*)d_in[1];
    float* out = (float*)d_out;
    double* partials = (double*)d_ws;   // NBLK * 4 doubles = 64 KB

    loss_main_kernel<<<NBLK, 256, 0, stream>>>(pred, target, partials);
    finalize_kernel<<<1, 256, 0, stream>>>(partials, out);
}

// Round 4
// 21.853 us; speedup vs baseline: 5.6504x; 1.2490x over previous
//
#include <hip/hip_runtime.h>

// CompositeLoss: boundary-weighted BCE + Dice over (32,1,512,512)
// pred: float32 uniform [0,1), target: int32 binary {0,1}
// out: [total, bce, dice] float32
//
// R3 = R1 (passed, absmax 0.0) + ONE change: halo columns come from
// neighbor lanes via __shfl (wave == one 512-px row since w8 == lane),
// replacing 6 uncoalesced scalar loads per segment. Equivalence:
//   oL = vertical-or of column w0-1 = neighbor lane's o7 (clamp: lane0 -> o0)
//   oR = vertical-or of column w0+8 = neighbor lane's o0 (clamp: lane63 -> o7)

#define BB 32
#define HH 512
#define WW 512
#define N_TOTAL (BB * HH * WW)
#define SEG 8
#define W8 (WW / SEG)            // 64 segments per row -> one wave per row
#define NSEG (BB * HH * W8)      // 1,048,576
#define NBLK 2048

__global__ __launch_bounds__(256) void loss_main_kernel(
        const float* __restrict__ pred,
        const int* __restrict__ target,
        double* __restrict__ partials) {
    float wbce = 0.f, inter = 0.f, sp = 0.f;
    int st_i = 0;

    const int lane = threadIdx.x & 63;
    const int stride = gridDim.x * blockDim.x;   // 524288 -> exactly 2 iters
    for (int seg = blockIdx.x * blockDim.x + threadIdx.x; seg < NSEG;
         seg += stride) {
        const int w0 = (seg & (W8 - 1)) << 3;    // == lane*8
        const int h  = (seg >> 6) & (HH - 1);
        const int b  = seg >> 15;

        const size_t rowbase = ((size_t)(b * HH + h)) * WW;

        const float4 p0 = *(const float4*)(pred + rowbase + w0);
        const float4 p1 = *(const float4*)(pred + rowbase + w0 + 4);

        const int* rowC = target + rowbase;                       // row h
        const int* rowU = (h > 0)      ? rowC - WW : rowC;        // row h-1 (clamped)
        const int* rowD = (h < HH - 1) ? rowC + WW : rowC;        // row h+1 (clamped)

        const int4 uA = *(const int4*)(rowU + w0);
        const int4 uB = *(const int4*)(rowU + w0 + 4);
        const int4 cA = *(const int4*)(rowC + w0);
        const int4 cB = *(const int4*)(rowC + w0 + 4);
        const int4 dA = *(const int4*)(rowD + w0);
        const int4 dB = *(const int4*)(rowD + w0 + 4);

        // vertical OR / AND (separable 3x3 morphology), all named
        const int o0 = uA.x | cA.x | dA.x,  n0 = uA.x & cA.x & dA.x;
        const int o1 = uA.y | cA.y | dA.y,  n1 = uA.y & cA.y & dA.y;
        const int o2 = uA.z | cA.z | dA.z,  n2 = uA.z & cA.z & dA.z;
        const int o3 = uA.w | cA.w | dA.w,  n3 = uA.w & cA.w & dA.w;
        const int o4 = uB.x | cB.x | dB.x,  n4 = uB.x & cB.x & dB.x;
        const int o5 = uB.y | cB.y | dB.y,  n5 = uB.y & cB.y & dB.y;
        const int o6 = uB.z | cB.z | dB.z,  n6 = uB.z & cB.z & dB.z;
        const int o7 = uB.w | cB.w | dB.w,  n7 = uB.w & cB.w & dB.w;

        // halo columns via shuffle (wave spans the whole row; w8 == lane)
        int oL = __shfl_up(o7, 1);
        int nL = __shfl_up(n7, 1);
        int oR = __shfl_down(o0, 1);
        int nR = __shfl_down(n0, 1);
        if (lane == 0)  { oL = o0; nL = n0; }   // clamp col -1 -> col 0
        if (lane == 63) { oR = o7; nR = n7; }   // clamp col 512 -> col 511

        // horizontal window -> boundary flag per pixel
        const int e0 = (oL | o0 | o1) != (nL & n0 & n1);
        const int e1 = (o0 | o1 | o2) != (n0 & n1 & n2);
        const int e2 = (o1 | o2 | o3) != (n1 & n2 & n3);
        const int e3 = (o2 | o3 | o4) != (n2 & n3 & n4);
        const int e4 = (o3 | o4 | o5) != (n3 & n4 & n5);
        const int e5 = (o4 | o5 | o6) != (n4 & n5 & n6);
        const int e6 = (o5 | o6 | o7) != (n5 & n6 & n7);
        const int e7 = (o6 | o7 | oR) != (n6 & n7 & nR);

#define ACC(T, P, E)                                                   \
        {                                                              \
            const float pc = fminf(fmaxf((P), 1e-7f), 1.0f - 1e-7f);   \
            const float x  = (T) ? pc : (1.0f - pc);                   \
            wbce += ((E) ? 3.0f : 1.0f) * (-__logf(x));                \
            sp += (P);                                                 \
            if (T) inter += (P);                                       \
            st_i += (T);                                               \
        }

        ACC(cA.x, p0.x, e0); ACC(cA.y, p0.y, e1);
        ACC(cA.z, p0.z, e2); ACC(cA.w, p0.w, e3);
        ACC(cB.x, p1.x, e4); ACC(cB.y, p1.y, e5);
        ACC(cB.z, p1.z, e6); ACC(cB.w, p1.w, e7);
#undef ACC
    }

    // wave (64-lane) shuffle reduction
    float st = (float)st_i;
    #pragma unroll
    for (int off = 32; off > 0; off >>= 1) {
        wbce  += __shfl_down(wbce,  off);
        inter += __shfl_down(inter, off);
        sp    += __shfl_down(sp,    off);
        st    += __shfl_down(st,    off);
    }

    __shared__ float smem[4][4];
    const int wave = threadIdx.x >> 6;
    if ((threadIdx.x & 63) == 0) {
        smem[wave][0] = wbce; smem[wave][1] = inter;
        smem[wave][2] = sp;   smem[wave][3] = st;
    }
    __syncthreads();
    if (threadIdx.x == 0) {
        float a0 = 0, a1 = 0, a2 = 0, a3 = 0;
        #pragma unroll
        for (int wv = 0; wv < 4; ++wv) {
            a0 += smem[wv][0]; a1 += smem[wv][1];
            a2 += smem[wv][2]; a3 += smem[wv][3];
        }
        double* dst = partials + (size_t)blockIdx.x * 4;
        dst[0] = (double)a0; dst[1] = (double)a1;
        dst[2] = (double)a2; dst[3] = (double)a3;
    }
}

__global__ __launch_bounds__(256) void finalize_kernel(
        const double* __restrict__ partials, float* __restrict__ out) {
    double a0 = 0, a1 = 0, a2 = 0, a3 = 0;
    #pragma unroll
    for (int k = 0; k < NBLK / 256; ++k) {
        const double* src = partials + (size_t)(k * 256 + threadIdx.x) * 4;
        a0 += src[0]; a1 += src[1]; a2 += src[2]; a3 += src[3];
    }
    #pragma unroll
    for (int off = 32; off > 0; off >>= 1) {
        a0 += __shfl_down(a0, off);
        a1 += __shfl_down(a1, off);
        a2 += __shfl_down(a2, off);
        a3 += __shfl_down(a3, off);
    }
    __shared__ double smem[4][4];
    const int wave = threadIdx.x >> 6;
    if ((threadIdx.x & 63) == 0) {
        smem[wave][0] = a0; smem[wave][1] = a1;
        smem[wave][2] = a2; smem[wave][3] = a3;
    }
    __syncthreads();
    if (threadIdx.x == 0) {
        double s0 = 0, s1 = 0, s2 = 0, s3 = 0;
        #pragma unroll
        for (int wv = 0; wv < 4; ++wv) {
            s0 += smem[wv][0]; s1 += smem[wv][1];
            s2 += smem[wv][2]; s3 += smem[wv][3];
        }
        const double bce = s0 / (double)N_TOTAL;
        const double dice_coef = (2.0 * s1 + 1e-6) / (s2 + s3 + 1e-6);
        const double dice = 1.0 - dice_coef;
        const double total = 0.5 * bce + 0.5 * dice;
        out[0] = (float)total;
        out[1] = (float)bce;
        out[2] = (float)dice;
    }
}

extern "C" void kernel_launch(void* const* d_in, const int* in_sizes, int n_in,
                              void* d_out, int out_size, void* d_ws, size_t ws_size,
                              hipStream_t stream) {
    const float* pred  = (const float*)d_in[0];
    const int* target  = (const int*)d_in[1];
    float* out = (float*)d_out;
    double* partials = (double*)d_ws;   // NBLK * 4 doubles = 64 KB

    loss_main_kernel<<<NBLK, 256, 0, stream>>>(pred, target, partials);
    finalize_kernel<<<1, 256, 0, stream>>>(partials, out);
}